// Round 11
// baseline (360.832 us; speedup 1.0000x reference)
//
#include <hip/hip_runtime.h>

#define N_NODES 100000
#define N_EDGES 1600000
#define IN_DIM 64
#define HID_DIM 128
#define EMB_DIM 64
#define NBUCK 782            // ceil(N_NODES / 128)
#define NBLK  256            // sort chunks
#define CHUNK 6250           // N_EDGES / NBLK
#define NTOT  (NBUCK * NBLK) // 200192 counts
#define G1B   1563           // ceil(N_NODES / 64) gemm1 tile blocks

typedef unsigned short ushortv8 __attribute__((ext_vector_type(8)));

__device__ __forceinline__ float bf2f(unsigned short u) {
    return __uint_as_float(((unsigned)u) << 16);
}
__device__ __forceinline__ unsigned short f2bf(float f) {
    unsigned u = __float_as_uint(f);
    unsigned r = (u + 0x7FFFu + ((u >> 16) & 1u)) >> 16;  // RNE
    return (unsigned short)r;
}

// ---------------- edge dtype handling ----------------
__global__ void k_detect_dtype(const unsigned int* __restrict__ ebuf, int* __restrict__ flag) {
    if (blockIdx.x == 0 && threadIdx.x == 0) {
        int is64 = 1;
        for (int i = 0; i < 64; ++i)
            if (ebuf[2 * i + 1] != 0u) { is64 = 0; break; }
        *flag = is64;
    }
}

__device__ __forceinline__ int edge_at(const void* eb, bool is64, long idx) {
    return is64 ? (int)((const long long*)eb)[idx] : ((const int*)eb)[idx];
}

// ------- fused: blocks [0,NBLK) = per-chunk histogram; rest = GEMM1 --------
__global__ __launch_bounds__(1024) void k_hist_gemm1(const void* __restrict__ eb,
                                                     const int* __restrict__ flag,
                                                     int* __restrict__ C,
                                                     const float4* __restrict__ x4,
                                                     const float4* __restrict__ W14,
                                                     ushort4* __restrict__ h1b4) {
    __shared__ char smem[49152]; // 48 KB, dual-purpose
    int b = blockIdx.x, t = threadIdx.x;
    if (b < NBLK) {
        int* h = (int*)smem;
        for (int i = t; i < NBUCK; i += 1024) h[i] = 0;
        __syncthreads();
        bool is64 = (*flag != 0);
        long e0 = (long)b * CHUNK;
        for (int i = t; i < CHUNK; i += 1024) {
            int c = edge_at(eb, is64, N_EDGES + e0 + i);
            atomicAdd(&h[c >> 7], 1);
        }
        __syncthreads();
        for (int i = t; i < NBUCK; i += 1024) C[i * NBLK + b] = h[i];
    } else {
        float4* sW4 = (float4*)smem;             // 32 KB
        float4* sX4 = (float4*)(smem + 32768);   // 16 KB (64 rows x 64 f)
        float*  sX  = (float*)sX4;
        long row0 = (long)(b - NBLK) * 64;
        for (int i = t; i < IN_DIM * HID_DIM / 4; i += 1024) sW4[i] = W14[i];
        {
            long base = row0 * (IN_DIM / 4);
            int rows = (int)min((long)64, (long)N_NODES - row0);
            if (t < rows * 16) sX4[t] = x4[base + t];
        }
        __syncthreads();
        int qc = t & 31;        // quad-col
        int r  = (t >> 5) * 2;  // rows r, r+1 within tile
        if (row0 + r >= N_NODES) return;
        float4 a0 = {0,0,0,0}, a1 = {0,0,0,0};
        for (int k = 0; k < IN_DIM; ++k) {
            float4 w = sW4[k * 32 + qc];
            float x0 = sX[r * IN_DIM + k];
            float x1 = sX[(r + 1) * IN_DIM + k];
            a0.x += x0 * w.x; a0.y += x0 * w.y; a0.z += x0 * w.z; a0.w += x0 * w.w;
            a1.x += x1 * w.x; a1.y += x1 * w.y; a1.z += x1 * w.z; a1.w += x1 * w.w;
        }
        ushort4 o0, o1;
        o0.x = f2bf(a0.x); o0.y = f2bf(a0.y); o0.z = f2bf(a0.z); o0.w = f2bf(a0.w);
        o1.x = f2bf(a1.x); o1.y = f2bf(a1.y); o1.z = f2bf(a1.z); o1.w = f2bf(a1.w);
        h1b4[(row0 + r) * 32 + qc] = o0;
        if (row0 + r + 1 < N_NODES) h1b4[(row0 + r + 1) * 32 + qc] = o1;
    }
}

// ------- hierarchical exclusive scan over NTOT counts ----------------------
__global__ __launch_bounds__(1024) void k_scan1(const int* __restrict__ src,
                                                int* __restrict__ dst,
                                                int* __restrict__ bsum, int n) {
    __shared__ int s[1024];
    int i = blockIdx.x * 1024 + threadIdx.x;
    int v = (i < n) ? src[i] : 0;
    s[threadIdx.x] = v;
    __syncthreads();
    for (int d = 1; d < 1024; d <<= 1) {
        int u = (threadIdx.x >= d) ? s[threadIdx.x - d] : 0;
        __syncthreads();
        s[threadIdx.x] += u;
        __syncthreads();
    }
    if (i < n) dst[i] = s[threadIdx.x] - v;  // exclusive within block
    if (threadIdx.x == 1023) bsum[blockIdx.x] = s[1023];
}

__global__ void k_scan2(int* __restrict__ bsum, int nb) {
    __shared__ int s[256];
    int t = threadIdx.x;
    int v = (t < nb) ? bsum[t] : 0;
    s[t] = v;
    __syncthreads();
    for (int d = 1; d < 256; d <<= 1) {
        int u = (t >= d) ? s[t - d] : 0;
        __syncthreads();
        s[t] += u;
        __syncthreads();
    }
    if (t < nb) bsum[t] = s[t] - v; // exclusive
}

__global__ __launch_bounds__(1024) void k_scan3(int* __restrict__ dst,
                                                const int* __restrict__ bsum, int n) {
    int i = blockIdx.x * 1024 + threadIdx.x;
    if (i < n) dst[i] += bsum[i >> 10];
}

// ------- scatter (LDS cursors, exact positions, no global atomics) ---------
__global__ __launch_bounds__(1024) void k_scatter2(const void* __restrict__ eb,
                                                   const int* __restrict__ flag,
                                                   const int* __restrict__ S,
                                                   unsigned* __restrict__ stage) {
    __shared__ int cur[NBUCK];
    int t = threadIdx.x, b = blockIdx.x;
    for (int i = t; i < NBUCK; i += 1024) cur[i] = S[i * NBLK + b];
    __syncthreads();
    bool is64 = (*flag != 0);
    long e0 = (long)b * CHUNK;
    for (int i = t; i < CHUNK; i += 1024) {
        int r = edge_at(eb, is64, e0 + i);
        int c = edge_at(eb, is64, N_EDGES + e0 + i);
        int p = atomicAdd(&cur[c >> 7], 1);          // LDS atomic
        stage[p] = (unsigned)r | ((unsigned)(c & 127) << 17);  // src<2^17
    }
}

// ------- per-bucket finalize: off[], dinv[], csr[] -------------------------
__global__ __launch_bounds__(256) void k_bfinal(const unsigned* __restrict__ stage,
                                                const int* __restrict__ S,
                                                int* __restrict__ off,
                                                float* __restrict__ dinv,
                                                int* __restrict__ csr) {
    __shared__ int h[128];
    __shared__ int lcur[128];
    int b = blockIdx.x;
    int t = threadIdx.x;
    int ebase = S[b * NBLK];
    int eend  = (b + 1 < NBUCK) ? S[(b + 1) * NBLK] : N_EDGES;
    if (t < 128) h[t] = 0;
    if (b == 0 && t == 0) off[N_NODES] = N_EDGES;
    __syncthreads();
    for (int i = ebase + t; i < eend; i += 256)
        atomicAdd(&h[stage[i] >> 17], 1);
    __syncthreads();
    int cnt = (t < 128) ? h[t] : 0;
    for (int d = 1; d < 128; d <<= 1) {
        int u = (t < 128 && t >= d) ? h[t - d] : 0;
        __syncthreads();
        if (t < 128) h[t] += u;
        __syncthreads();
    }
    if (t < 128) {
        int node = b * 128 + t;
        int excl = h[t] - cnt;
        lcur[t] = ebase + excl;
        if (node < N_NODES) {
            off[node]  = ebase + excl;
            dinv[node] = rsqrtf((float)(cnt + 1));  // +1 self loop
        }
    }
    __syncthreads();
    for (int i = ebase + t; i < eend; i += 256) {
        unsigned u = stage[i];
        int p = atomicAdd(&lcur[u >> 17], 1);
        csr[p] = (int)(u & 0x1FFFFu);
    }
}

// ------- agg1: two channel-phases (working set 12.8 MB each) ---------------
// Phase p handles channels [p*64, p*64+64). 8 lane-groups x 8 lanes x 16B.
__global__ __launch_bounds__(256) void k_agg1(const int* __restrict__ off,
                                              const int* __restrict__ csr,
                                              const float* __restrict__ dinv,
                                              const ushortv8* __restrict__ h1b,
                                              const float4* __restrict__ b14,
                                              float4* __restrict__ agg1) {
    const int nb4 = (N_NODES + 3) / 4;
    int bb = blockIdx.x;
    int phase = (bb >= nb4) ? 1 : 0;
    int node = (bb - phase * nb4) * 4 + (threadIdx.x >> 6);
    if (node >= N_NODES) return;
    int lane = threadIdx.x & 63;
    int grp  = lane >> 3;               // 0..7
    int cpos = lane & 7;                // within-half ushort8 slot
    int slot = phase * 8 + cpos;        // of 16 per row
    int ebase = off[node];
    int deg   = off[node + 1] - ebase;
    float dc  = dinv[node];
    float acc[8] = {0.f, 0.f, 0.f, 0.f, 0.f, 0.f, 0.f, 0.f};
    int i = grp;
    for (; i + 24 < deg; i += 32) {     // 4 edges/group in flight, stride 8
        int s0 = csr[ebase + i + 0];
        int s1 = csr[ebase + i + 8];
        int s2 = csr[ebase + i + 16];
        int s3 = csr[ebase + i + 24];
        float n0 = dc * dinv[s0], n1 = dc * dinv[s1];
        float n2 = dc * dinv[s2], n3 = dc * dinv[s3];
        ushortv8 v0 = h1b[(long)s0 * 16 + slot];
        ushortv8 v1 = h1b[(long)s1 * 16 + slot];
        ushortv8 v2 = h1b[(long)s2 * 16 + slot];
        ushortv8 v3 = h1b[(long)s3 * 16 + slot];
#pragma unroll
        for (int j = 0; j < 8; ++j) acc[j] += n0 * bf2f(v0[j]);
#pragma unroll
        for (int j = 0; j < 8; ++j) acc[j] += n1 * bf2f(v1[j]);
#pragma unroll
        for (int j = 0; j < 8; ++j) acc[j] += n2 * bf2f(v2[j]);
#pragma unroll
        for (int j = 0; j < 8; ++j) acc[j] += n3 * bf2f(v3[j]);
    }
    for (; i < deg; i += 8) {
        int s = csr[ebase + i];
        float n = dc * dinv[s];
        ushortv8 v = h1b[(long)s * 16 + slot];
#pragma unroll
        for (int j = 0; j < 8; ++j) acc[j] += n * bf2f(v[j]);
    }
#pragma unroll
    for (int j = 0; j < 8; ++j) {
        acc[j] += __shfl_xor(acc[j], 8);
        acc[j] += __shfl_xor(acc[j], 16);
        acc[j] += __shfl_xor(acc[j], 32);
    }
    if (grp == 0) {
        float s = dc * dc;
        ushortv8 hs = h1b[(long)node * 16 + slot];
        float4 b0 = b14[phase * 16 + 2 * cpos], b1 = b14[phase * 16 + 2 * cpos + 1];
        float4 o0, o1;
        o0.x = b0.x + s * bf2f(hs[0]) + acc[0];
        o0.y = b0.y + s * bf2f(hs[1]) + acc[1];
        o0.z = b0.z + s * bf2f(hs[2]) + acc[2];
        o0.w = b0.w + s * bf2f(hs[3]) + acc[3];
        o1.x = b1.x + s * bf2f(hs[4]) + acc[4];
        o1.y = b1.y + s * bf2f(hs[5]) + acc[5];
        o1.z = b1.z + s * bf2f(hs[6]) + acc[6];
        o1.w = b1.w + s * bf2f(hs[7]) + acc[7];
        agg1[(long)node * 32 + phase * 16 + 2 * cpos]     = o0;
        agg1[(long)node * 32 + phase * 16 + 2 * cpos + 1] = o1;
    }
}

// ------- GEMM2: h2b = bf16(relu(agg1) @ W2)  (100000x128 @ 128x64) --------
__global__ __launch_bounds__(256) void k_gemm2(const float4* __restrict__ agg14,
                                               const float4* __restrict__ W24,
                                               ushort4* __restrict__ h2b4) {
    __shared__ float sW[HID_DIM * EMB_DIM]; // 32 KB
    __shared__ float sH[32 * HID_DIM];      // 16 KB
    float4* sW4 = (float4*)sW;
    float4* sH4 = (float4*)sH;
    int t = threadIdx.x;
    long row0 = (long)blockIdx.x * 32;
    for (int i = t; i < HID_DIM * EMB_DIM / 4; i += 256) sW4[i] = W24[i];
    for (int i = t; i < 32 * HID_DIM / 4; i += 256) {
        float4 v = agg14[row0 * (HID_DIM / 4) + i];
        v.x = fmaxf(v.x, 0.f); v.y = fmaxf(v.y, 0.f);
        v.z = fmaxf(v.z, 0.f); v.w = fmaxf(v.w, 0.f);
        sH4[i] = v;
    }
    __syncthreads();
    int qc = t & 15;
    int r  = (t >> 4) * 2;
    float4 a0 = {0,0,0,0}, a1 = {0,0,0,0};
    for (int k = 0; k < HID_DIM; ++k) {
        float4 w = sW4[k * 16 + qc];
        float x0 = sH[r * HID_DIM + k];
        float x1 = sH[(r + 1) * HID_DIM + k];
        a0.x += x0 * w.x; a0.y += x0 * w.y; a0.z += x0 * w.z; a0.w += x0 * w.w;
        a1.x += x1 * w.x; a1.y += x1 * w.y; a1.z += x1 * w.z; a1.w += x1 * w.w;
    }
    ushort4 o0, o1;
    o0.x = f2bf(a0.x); o0.y = f2bf(a0.y); o0.z = f2bf(a0.z); o0.w = f2bf(a0.w);
    o1.x = f2bf(a1.x); o1.y = f2bf(a1.y); o1.z = f2bf(a1.z); o1.w = f2bf(a1.w);
    h2b4[(row0 + r) * 16 + qc]     = o0;
    h2b4[(row0 + r + 1) * 16 + qc] = o1;
}

// ------- agg2: two channel-phases; 16 groups x 4 lanes x 16B ---------------
__global__ __launch_bounds__(256) void k_agg2(const int* __restrict__ off,
                                              const int* __restrict__ csr,
                                              const float* __restrict__ dinv,
                                              const ushortv8* __restrict__ h2b,
                                              const float4* __restrict__ b24,
                                              float4* __restrict__ out) {
    const int nb4 = (N_NODES + 3) / 4;
    int bb = blockIdx.x;
    int phase = (bb >= nb4) ? 1 : 0;
    int node = (bb - phase * nb4) * 4 + (threadIdx.x >> 6);
    if (node >= N_NODES) return;
    int lane = threadIdx.x & 63;
    int grp  = lane >> 2;               // 0..15
    int cpos = lane & 3;                // within-half ushort8 slot
    int slot = phase * 4 + cpos;        // of 8 per row
    int ebase = off[node];
    int deg   = off[node + 1] - ebase;
    float dc  = dinv[node];
    float acc[8] = {0.f, 0.f, 0.f, 0.f, 0.f, 0.f, 0.f, 0.f};
    int i = grp;
    for (; i + 48 < deg; i += 64) {     // 4 edges/group in flight, stride 16
        int s0 = csr[ebase + i + 0];
        int s1 = csr[ebase + i + 16];
        int s2 = csr[ebase + i + 32];
        int s3 = csr[ebase + i + 48];
        float n0 = dc * dinv[s0], n1 = dc * dinv[s1];
        float n2 = dc * dinv[s2], n3 = dc * dinv[s3];
        ushortv8 v0 = h2b[(long)s0 * 8 + slot];
        ushortv8 v1 = h2b[(long)s1 * 8 + slot];
        ushortv8 v2 = h2b[(long)s2 * 8 + slot];
        ushortv8 v3 = h2b[(long)s3 * 8 + slot];
#pragma unroll
        for (int j = 0; j < 8; ++j) acc[j] += n0 * bf2f(v0[j]);
#pragma unroll
        for (int j = 0; j < 8; ++j) acc[j] += n1 * bf2f(v1[j]);
#pragma unroll
        for (int j = 0; j < 8; ++j) acc[j] += n2 * bf2f(v2[j]);
#pragma unroll
        for (int j = 0; j < 8; ++j) acc[j] += n3 * bf2f(v3[j]);
    }
    for (; i < deg; i += 16) {
        int s = csr[ebase + i];
        float n = dc * dinv[s];
        ushortv8 v = h2b[(long)s * 8 + slot];
#pragma unroll
        for (int j = 0; j < 8; ++j) acc[j] += n * bf2f(v[j]);
    }
#pragma unroll
    for (int j = 0; j < 8; ++j) {
        acc[j] += __shfl_xor(acc[j], 4);
        acc[j] += __shfl_xor(acc[j], 8);
        acc[j] += __shfl_xor(acc[j], 16);
        acc[j] += __shfl_xor(acc[j], 32);
    }
    if (grp == 0) {
        float s = dc * dc;
        ushortv8 hs = h2b[(long)node * 8 + slot];
        float4 b0 = b24[phase * 8 + 2 * cpos], b1 = b24[phase * 8 + 2 * cpos + 1];
        float4 o0, o1;
        o0.x = b0.x + s * bf2f(hs[0]) + acc[0];
        o0.y = b0.y + s * bf2f(hs[1]) + acc[1];
        o0.z = b0.z + s * bf2f(hs[2]) + acc[2];
        o0.w = b0.w + s * bf2f(hs[3]) + acc[3];
        o1.x = b1.x + s * bf2f(hs[4]) + acc[4];
        o1.y = b1.y + s * bf2f(hs[5]) + acc[5];
        o1.z = b1.z + s * bf2f(hs[6]) + acc[6];
        o1.w = b1.w + s * bf2f(hs[7]) + acc[7];
        out[(long)node * 16 + phase * 8 + 2 * cpos]     = o0;
        out[(long)node * 16 + phase * 8 + 2 * cpos + 1] = o1;
    }
}

extern "C" void kernel_launch(void* const* d_in, const int* in_sizes, int n_in,
                              void* d_out, int out_size, void* d_ws, size_t ws_size,
                              hipStream_t stream) {
    const float* x   = (const float*)d_in[0];
    const void*  eb  = d_in[1];
    const float* W1  = (const float*)d_in[2];
    const float* b1  = (const float*)d_in[3];
    const float* W2  = (const float*)d_in[4];
    const float* b2  = (const float*)d_in[5];
    float* out = (float*)d_out;

    // Workspace layout (bytes):
    char* ws = (char*)d_ws;
    int*            flag  = (int*)     (ws + 0);          //        16
    int*            bsum  = (int*)     (ws + 64);         //       784 (196 ints)
    int*            C     = (int*)     (ws + 1024);       //   800,768
    int*            S     = (int*)     (ws + 802816);     //   800,768
    int*            off   = (int*)     (ws + 1605632);    //   400,004
    float*          dinv  = (float*)   (ws + 2005760);    //   400,000
    unsigned*       stage = (unsigned*)(ws + 2405760);    // 6,400,000
    int*            csr   = (int*)     (ws + 8805760);    // 6,400,000
    unsigned short* h1b   = (unsigned short*)(ws + 15205760); // 25,600,000
    unsigned short* h2b   = (unsigned short*)(ws + 15205760); // alias h1b (dead after agg1)
    float*          agg1  = (float*)   (ws + 40805760);   // 51,200,000 (end ~92.0 MB)

    k_detect_dtype<<<1, 64, 0, stream>>>((const unsigned int*)eb, flag);
    k_hist_gemm1<<<NBLK + G1B, 1024, 0, stream>>>(eb, flag, C,
                                                  (const float4*)x, (const float4*)W1,
                                                  (ushort4*)h1b);
    const int nsb = (NTOT + 1023) / 1024;   // 196
    k_scan1<<<nsb, 1024, 0, stream>>>(C, S, bsum, NTOT);
    k_scan2<<<1, 256, 0, stream>>>(bsum, nsb);
    k_scan3<<<nsb, 1024, 0, stream>>>(S, bsum, NTOT);
    k_scatter2<<<NBLK, 1024, 0, stream>>>(eb, flag, S, stage);
    k_bfinal<<<NBUCK, 256, 0, stream>>>(stage, S, off, dinv, csr);

    const int nb4 = (N_NODES + 3) / 4;
    k_agg1<<<2 * nb4, 256, 0, stream>>>(off, csr, dinv,
                                        (const ushortv8*)h1b, (const float4*)b1,
                                        (float4*)agg1);

    k_gemm2<<<N_NODES / 32, 256, 0, stream>>>((const float4*)agg1, (const float4*)W2,
                                              (ushort4*)h2b);
    k_agg2<<<2 * nb4, 256, 0, stream>>>(off, csr, dinv,
                                        (const ushortv8*)h2b, (const float4*)b2,
                                        (float4*)out);
}

// Round 12
// 302.320 us; speedup vs baseline: 1.1935x; 1.1935x over previous
//
#include <hip/hip_runtime.h>

#define N_NODES 100000
#define N_EDGES 1600000
#define IN_DIM 64
#define HID_DIM 128
#define EMB_DIM 64
#define NBUCK 782            // ceil(N_NODES / 128)
#define NBLK  256            // sort chunks
#define CHUNK 6250           // N_EDGES / NBLK
#define NTOT  (NBUCK * NBLK) // 200192 counts

typedef unsigned short ushortv8 __attribute__((ext_vector_type(8)));

__device__ __forceinline__ float bf2f(unsigned short u) {
    return __uint_as_float(((unsigned)u) << 16);
}
__device__ __forceinline__ unsigned short f2bf(float f) {
    unsigned u = __float_as_uint(f);
    unsigned r = (u + 0x7FFFu + ((u >> 16) & 1u)) >> 16;  // RNE
    return (unsigned short)r;
}

// ---------------- edge dtype handling ----------------
__global__ void k_detect_dtype(const unsigned int* __restrict__ ebuf, int* __restrict__ flag) {
    if (blockIdx.x == 0 && threadIdx.x == 0) {
        int is64 = 1;
        for (int i = 0; i < 64; ++i)
            if (ebuf[2 * i + 1] != 0u) { is64 = 0; break; }
        *flag = is64;
    }
}

__device__ __forceinline__ int edge_at(const void* eb, bool is64, long idx) {
    return is64 ? (int)((const long long*)eb)[idx] : ((const int*)eb)[idx];
}

// ------- pass 1: per-(chunk-block, bucket) histogram via LDS ---------------
__global__ __launch_bounds__(1024) void k_hist(const void* __restrict__ eb,
                                               const int* __restrict__ flag,
                                               int* __restrict__ C) {
    __shared__ int h[NBUCK];
    int t = threadIdx.x, b = blockIdx.x;
    for (int i = t; i < NBUCK; i += 1024) h[i] = 0;
    __syncthreads();
    bool is64 = (*flag != 0);
    long e0 = (long)b * CHUNK;
    for (int i = t; i < CHUNK; i += 1024) {
        int c = edge_at(eb, is64, N_EDGES + e0 + i);
        atomicAdd(&h[c >> 7], 1);
    }
    __syncthreads();
    for (int i = t; i < NBUCK; i += 1024) C[i * NBLK + b] = h[i];
}

// ------- hierarchical exclusive scan over NTOT counts ----------------------
__global__ __launch_bounds__(1024) void k_scan1(const int* __restrict__ src,
                                                int* __restrict__ dst,
                                                int* __restrict__ bsum, int n) {
    __shared__ int s[1024];
    int i = blockIdx.x * 1024 + threadIdx.x;
    int v = (i < n) ? src[i] : 0;
    s[threadIdx.x] = v;
    __syncthreads();
    for (int d = 1; d < 1024; d <<= 1) {
        int u = (threadIdx.x >= d) ? s[threadIdx.x - d] : 0;
        __syncthreads();
        s[threadIdx.x] += u;
        __syncthreads();
    }
    if (i < n) dst[i] = s[threadIdx.x] - v;  // exclusive within block
    if (threadIdx.x == 1023) bsum[blockIdx.x] = s[1023];
}

__global__ void k_scan2(int* __restrict__ bsum, int nb) {
    __shared__ int s[256];
    int t = threadIdx.x;
    int v = (t < nb) ? bsum[t] : 0;
    s[t] = v;
    __syncthreads();
    for (int d = 1; d < 256; d <<= 1) {
        int u = (t >= d) ? s[t - d] : 0;
        __syncthreads();
        s[t] += u;
        __syncthreads();
    }
    if (t < nb) bsum[t] = s[t] - v; // exclusive
}

__global__ __launch_bounds__(1024) void k_scan3(int* __restrict__ dst,
                                                const int* __restrict__ bsum, int n) {
    int i = blockIdx.x * 1024 + threadIdx.x;
    if (i < n) dst[i] += bsum[i >> 10];
}

// ------- scatter (LDS cursors, exact positions, no global atomics) ---------
__global__ __launch_bounds__(1024) void k_scatter2(const void* __restrict__ eb,
                                                   const int* __restrict__ flag,
                                                   const int* __restrict__ S,
                                                   unsigned* __restrict__ stage) {
    __shared__ int cur[NBUCK];
    int t = threadIdx.x, b = blockIdx.x;
    for (int i = t; i < NBUCK; i += 1024) cur[i] = S[i * NBLK + b];
    __syncthreads();
    bool is64 = (*flag != 0);
    long e0 = (long)b * CHUNK;
    for (int i = t; i < CHUNK; i += 1024) {
        int r = edge_at(eb, is64, e0 + i);
        int c = edge_at(eb, is64, N_EDGES + e0 + i);
        int p = atomicAdd(&cur[c >> 7], 1);          // LDS atomic
        stage[p] = (unsigned)r | ((unsigned)(c & 127) << 17);  // src<2^17
    }
}

// ------- per-bucket finalize: off[], dinv[], csr[] -------------------------
__global__ __launch_bounds__(256) void k_bfinal(const unsigned* __restrict__ stage,
                                                const int* __restrict__ S,
                                                int* __restrict__ off,
                                                float* __restrict__ dinv,
                                                int* __restrict__ csr) {
    __shared__ int h[128];
    __shared__ int lcur[128];
    int b = blockIdx.x;
    int t = threadIdx.x;
    int ebase = S[b * NBLK];
    int eend  = (b + 1 < NBUCK) ? S[(b + 1) * NBLK] : N_EDGES;
    if (t < 128) h[t] = 0;
    if (b == 0 && t == 0) off[N_NODES] = N_EDGES;
    __syncthreads();
    for (int i = ebase + t; i < eend; i += 256)
        atomicAdd(&h[stage[i] >> 17], 1);
    __syncthreads();
    int cnt = (t < 128) ? h[t] : 0;
    for (int d = 1; d < 128; d <<= 1) {
        int u = (t < 128 && t >= d) ? h[t - d] : 0;
        __syncthreads();
        if (t < 128) h[t] += u;
        __syncthreads();
    }
    if (t < 128) {
        int node = b * 128 + t;
        int excl = h[t] - cnt;
        lcur[t] = ebase + excl;
        if (node < N_NODES) {
            off[node]  = ebase + excl;
            dinv[node] = rsqrtf((float)(cnt + 1));  // +1 self loop
        }
    }
    __syncthreads();
    for (int i = ebase + t; i < eend; i += 256) {
        unsigned u = stage[i];
        int p = atomicAdd(&lcur[u >> 17], 1);
        csr[p] = (int)(u & 0x1FFFFu);
    }
}

// ------- cast x (f32) -> xb (bf16), vectorized -----------------------------
__global__ __launch_bounds__(256) void k_cast(const float4* __restrict__ x4,
                                              ushort4* __restrict__ xb4) {
    long i = (long)blockIdx.x * 256 + threadIdx.x;   // over N*16
    if (i < (long)N_NODES * (IN_DIM / 4)) {
        float4 v = x4[i];
        ushort4 o;
        o.x = f2bf(v.x); o.y = f2bf(v.y); o.z = f2bf(v.z); o.w = f2bf(v.w);
        xb4[i] = o;
    }
}

// ------- aggx: aggregate x BEFORE W1 (64 ch): A(XW) = (AX)W ----------------
// 1 wave/node; 8 lane-groups x 8 lanes x ushort8 (16B); x4 strided unroll.
__global__ __launch_bounds__(256) void k_aggx(const int* __restrict__ off,
                                              const int* __restrict__ csr,
                                              const float* __restrict__ dinv,
                                              const ushortv8* __restrict__ xb,
                                              float4* __restrict__ aggx) {
    int node = blockIdx.x * 4 + (threadIdx.x >> 6);
    if (node >= N_NODES) return;
    int lane = threadIdx.x & 63;
    int grp  = lane >> 3;   // 0..7
    int cpos = lane & 7;    // ushort8 slot: channels 8*cpos..8*cpos+7
    int ebase = off[node];
    int deg   = off[node + 1] - ebase;
    float dc  = dinv[node];
    float acc[8] = {0.f, 0.f, 0.f, 0.f, 0.f, 0.f, 0.f, 0.f};
    int i = grp;
    for (; i + 24 < deg; i += 32) {   // 4 edges per group in flight, stride 8
        int s0 = csr[ebase + i + 0];
        int s1 = csr[ebase + i + 8];
        int s2 = csr[ebase + i + 16];
        int s3 = csr[ebase + i + 24];
        float n0 = dc * dinv[s0], n1 = dc * dinv[s1];
        float n2 = dc * dinv[s2], n3 = dc * dinv[s3];
        ushortv8 v0 = xb[(long)s0 * 8 + cpos];
        ushortv8 v1 = xb[(long)s1 * 8 + cpos];
        ushortv8 v2 = xb[(long)s2 * 8 + cpos];
        ushortv8 v3 = xb[(long)s3 * 8 + cpos];
#pragma unroll
        for (int j = 0; j < 8; ++j) acc[j] += n0 * bf2f(v0[j]);
#pragma unroll
        for (int j = 0; j < 8; ++j) acc[j] += n1 * bf2f(v1[j]);
#pragma unroll
        for (int j = 0; j < 8; ++j) acc[j] += n2 * bf2f(v2[j]);
#pragma unroll
        for (int j = 0; j < 8; ++j) acc[j] += n3 * bf2f(v3[j]);
    }
    for (; i < deg; i += 8) {
        int s = csr[ebase + i];
        float n = dc * dinv[s];
        ushortv8 v = xb[(long)s * 8 + cpos];
#pragma unroll
        for (int j = 0; j < 8; ++j) acc[j] += n * bf2f(v[j]);
    }
#pragma unroll
    for (int j = 0; j < 8; ++j) {
        acc[j] += __shfl_xor(acc[j], 8);
        acc[j] += __shfl_xor(acc[j], 16);
        acc[j] += __shfl_xor(acc[j], 32);
    }
    if (grp == 0) {
        float s = dc * dc;
        ushortv8 hs = xb[(long)node * 8 + cpos];
        float4 o0, o1;
        o0.x = s * bf2f(hs[0]) + acc[0];
        o0.y = s * bf2f(hs[1]) + acc[1];
        o0.z = s * bf2f(hs[2]) + acc[2];
        o0.w = s * bf2f(hs[3]) + acc[3];
        o1.x = s * bf2f(hs[4]) + acc[4];
        o1.y = s * bf2f(hs[5]) + acc[5];
        o1.z = s * bf2f(hs[6]) + acc[6];
        o1.w = s * bf2f(hs[7]) + acc[7];
        aggx[(long)node * 16 + 2 * cpos]     = o0;
        aggx[(long)node * 16 + 2 * cpos + 1] = o1;
    }
}

// ------- GEMM-A: agg1 = aggx @ W1 + b1  (100000x64 @ 64x128, f32 out) ------
__global__ __launch_bounds__(256) void k_gemma(const float4* __restrict__ aggx4,
                                               const float4* __restrict__ W14,
                                               const float4* __restrict__ b14,
                                               float4* __restrict__ agg14) {
    __shared__ float sW[IN_DIM * HID_DIM]; // 32 KB
    __shared__ float sX[16 * IN_DIM];      // 4 KB
    float4* sW4 = (float4*)sW;
    float4* sX4 = (float4*)sX;
    int t = threadIdx.x;
    long row0 = (long)blockIdx.x * 16;
    for (int i = t; i < IN_DIM * HID_DIM / 4; i += 256) sW4[i] = W14[i];
    sX4[t] = aggx4[row0 * (IN_DIM / 4) + t];  // 256 float4 = 16 rows
    __syncthreads();
    int qc = t & 31;        // quad-col: cols [4qc..4qc+3]
    int r  = (t >> 5) * 2;  // rows r, r+1
    float4 b = b14[qc];
    float4 a0 = b, a1 = b;
    for (int k = 0; k < IN_DIM; ++k) {
        float4 w = sW4[k * 32 + qc];
        float x0 = sX[r * IN_DIM + k];
        float x1 = sX[(r + 1) * IN_DIM + k];
        a0.x += x0 * w.x; a0.y += x0 * w.y; a0.z += x0 * w.z; a0.w += x0 * w.w;
        a1.x += x1 * w.x; a1.y += x1 * w.y; a1.z += x1 * w.z; a1.w += x1 * w.w;
    }
    agg14[(row0 + r) * 32 + qc]     = a0;
    agg14[(row0 + r + 1) * 32 + qc] = a1;
}

// ------- GEMM2: h2b = bf16(relu(agg1) @ W2)  (100000x128 @ 128x64) --------
__global__ __launch_bounds__(256) void k_gemm2(const float4* __restrict__ agg14,
                                               const float4* __restrict__ W24,
                                               ushort4* __restrict__ h2b4) {
    __shared__ float sW[HID_DIM * EMB_DIM]; // 32 KB
    __shared__ float sH[32 * HID_DIM];      // 16 KB
    float4* sW4 = (float4*)sW;
    float4* sH4 = (float4*)sH;
    int t = threadIdx.x;
    long row0 = (long)blockIdx.x * 32;
    for (int i = t; i < HID_DIM * EMB_DIM / 4; i += 256) sW4[i] = W24[i];
    for (int i = t; i < 32 * HID_DIM / 4; i += 256) {
        float4 v = agg14[row0 * (HID_DIM / 4) + i];
        v.x = fmaxf(v.x, 0.f); v.y = fmaxf(v.y, 0.f);
        v.z = fmaxf(v.z, 0.f); v.w = fmaxf(v.w, 0.f);
        sH4[i] = v;
    }
    __syncthreads();
    int qc = t & 15;
    int r  = (t >> 4) * 2;
    float4 a0 = {0,0,0,0}, a1 = {0,0,0,0};
    for (int k = 0; k < HID_DIM; ++k) {
        float4 w = sW4[k * 16 + qc];
        float x0 = sH[r * HID_DIM + k];
        float x1 = sH[(r + 1) * HID_DIM + k];
        a0.x += x0 * w.x; a0.y += x0 * w.y; a0.z += x0 * w.z; a0.w += x0 * w.w;
        a1.x += x1 * w.x; a1.y += x1 * w.y; a1.z += x1 * w.z; a1.w += x1 * w.w;
    }
    ushort4 o0, o1;
    o0.x = f2bf(a0.x); o0.y = f2bf(a0.y); o0.z = f2bf(a0.z); o0.w = f2bf(a0.w);
    o1.x = f2bf(a1.x); o1.y = f2bf(a1.y); o1.z = f2bf(a1.z); o1.w = f2bf(a1.w);
    h2b4[(row0 + r) * 16 + qc]     = o0;
    h2b4[(row0 + r + 1) * 16 + qc] = o1;
}

// ------- agg2: 1 wave/node; 8 lane-groups x ushort8; x4 unroll (R7 form) ---
__global__ __launch_bounds__(256) void k_agg2(const int* __restrict__ off,
                                              const int* __restrict__ csr,
                                              const float* __restrict__ dinv,
                                              const ushortv8* __restrict__ h2b,
                                              const float4* __restrict__ b24,
                                              float4* __restrict__ out) {
    int node = blockIdx.x * 4 + (threadIdx.x >> 6);
    if (node >= N_NODES) return;
    int lane = threadIdx.x & 63;
    int grp  = lane >> 3;   // 0..7
    int cpos = lane & 7;    // ushort8 slot: channels 8*cpos..8*cpos+7
    int ebase = off[node];
    int deg   = off[node + 1] - ebase;
    float dc  = dinv[node];
    float acc[8] = {0.f, 0.f, 0.f, 0.f, 0.f, 0.f, 0.f, 0.f};
    int i = grp;
    for (; i + 24 < deg; i += 32) {   // 4 edges per group in flight, stride 8
        int s0 = csr[ebase + i + 0];
        int s1 = csr[ebase + i + 8];
        int s2 = csr[ebase + i + 16];
        int s3 = csr[ebase + i + 24];
        float n0 = dc * dinv[s0], n1 = dc * dinv[s1];
        float n2 = dc * dinv[s2], n3 = dc * dinv[s3];
        ushortv8 v0 = h2b[(long)s0 * 8 + cpos];
        ushortv8 v1 = h2b[(long)s1 * 8 + cpos];
        ushortv8 v2 = h2b[(long)s2 * 8 + cpos];
        ushortv8 v3 = h2b[(long)s3 * 8 + cpos];
#pragma unroll
        for (int j = 0; j < 8; ++j) acc[j] += n0 * bf2f(v0[j]);
#pragma unroll
        for (int j = 0; j < 8; ++j) acc[j] += n1 * bf2f(v1[j]);
#pragma unroll
        for (int j = 0; j < 8; ++j) acc[j] += n2 * bf2f(v2[j]);
#pragma unroll
        for (int j = 0; j < 8; ++j) acc[j] += n3 * bf2f(v3[j]);
    }
    for (; i < deg; i += 8) {
        int s = csr[ebase + i];
        float n = dc * dinv[s];
        ushortv8 v = h2b[(long)s * 8 + cpos];
#pragma unroll
        for (int j = 0; j < 8; ++j) acc[j] += n * bf2f(v[j]);
    }
#pragma unroll
    for (int j = 0; j < 8; ++j) {
        acc[j] += __shfl_xor(acc[j], 8);
        acc[j] += __shfl_xor(acc[j], 16);
        acc[j] += __shfl_xor(acc[j], 32);
    }
    if (grp == 0) {
        float s = dc * dc;
        ushortv8 hs = h2b[(long)node * 8 + cpos];
        float4 b0 = b24[2 * cpos], b1 = b24[2 * cpos + 1];
        float4 o0, o1;
        o0.x = b0.x + s * bf2f(hs[0]) + acc[0];
        o0.y = b0.y + s * bf2f(hs[1]) + acc[1];
        o0.z = b0.z + s * bf2f(hs[2]) + acc[2];
        o0.w = b0.w + s * bf2f(hs[3]) + acc[3];
        o1.x = b1.x + s * bf2f(hs[4]) + acc[4];
        o1.y = b1.y + s * bf2f(hs[5]) + acc[5];
        o1.z = b1.z + s * bf2f(hs[6]) + acc[6];
        o1.w = b1.w + s * bf2f(hs[7]) + acc[7];
        out[(long)node * 16 + 2 * cpos]     = o0;
        out[(long)node * 16 + 2 * cpos + 1] = o1;
    }
}

extern "C" void kernel_launch(void* const* d_in, const int* in_sizes, int n_in,
                              void* d_out, int out_size, void* d_ws, size_t ws_size,
                              hipStream_t stream) {
    const float* x   = (const float*)d_in[0];
    const void*  eb  = d_in[1];
    const float* W1  = (const float*)d_in[2];
    const float* b1  = (const float*)d_in[3];
    const float* W2  = (const float*)d_in[4];
    const float* b2  = (const float*)d_in[5];
    float* out = (float*)d_out;

    // Workspace layout (bytes):
    char* ws = (char*)d_ws;
    int*            flag  = (int*)     (ws + 0);          //        16
    int*            bsum  = (int*)     (ws + 64);         //       784 (196 ints)
    int*            C     = (int*)     (ws + 1024);       //   800,768
    int*            S     = (int*)     (ws + 802816);     //   800,768
    int*            off   = (int*)     (ws + 1605632);    //   400,004
    float*          dinv  = (float*)   (ws + 2005760);    //   400,000
    unsigned*       stage = (unsigned*)(ws + 2405760);    // 6,400,000
    int*            csr   = (int*)     (ws + 8805760);    // 6,400,000
    unsigned short* xb    = (unsigned short*)(ws + 15205760); // 12,800,000
    unsigned short* h2b   = (unsigned short*)(ws + 15205760); // alias xb (dead after aggx)
    float*          aggx  = (float*)   (ws + 28005760);   // 25,600,000
    float*          agg1  = (float*)   (ws + 53605760);   // 51,200,000 (end ~104.8 MB)

    k_detect_dtype<<<1, 64, 0, stream>>>((const unsigned int*)eb, flag);
    k_hist<<<NBLK, 1024, 0, stream>>>(eb, flag, C);
    const int nsb = (NTOT + 1023) / 1024;   // 196
    k_scan1<<<nsb, 1024, 0, stream>>>(C, S, bsum, NTOT);
    k_scan2<<<1, 256, 0, stream>>>(bsum, nsb);
    k_scan3<<<nsb, 1024, 0, stream>>>(S, bsum, NTOT);
    k_scatter2<<<NBLK, 1024, 0, stream>>>(eb, flag, S, stage);
    k_bfinal<<<NBUCK, 256, 0, stream>>>(stage, S, off, dinv, csr);

    k_cast<<<(N_NODES * 16 + 255) / 256, 256, 0, stream>>>((const float4*)x, (ushort4*)xb);
    k_aggx<<<(N_NODES + 3) / 4, 256, 0, stream>>>(off, csr, dinv,
                                                  (const ushortv8*)xb, (float4*)aggx);
    k_gemma<<<N_NODES / 16, 256, 0, stream>>>((const float4*)aggx, (const float4*)W1,
                                              (const float4*)b1, (float4*)agg1);

    k_gemm2<<<N_NODES / 32, 256, 0, stream>>>((const float4*)agg1, (const float4*)W2,
                                              (ushort4*)h2b);
    k_agg2<<<(N_NODES + 3) / 4, 256, 0, stream>>>(off, csr, dinv,
                                                  (const ushortv8*)h2b, (const float4*)b2,
                                                  (float4*)out);
}